// Round 1
// baseline (72.136 us; speedup 1.0000x reference)
//
#include <hip/hip_runtime.h>

#define EPS_C 0.0009f   // 0.03^2

__device__ __forceinline__ float metric_val(float dot, float f, float g) {
    float c    = dot / (f * g);
    float dn   = sqrtf(fmaxf(2.0f - 2.0f * c, 0.0f));
    float dist = (2.0f - dn) * 0.5f;
    float lum  = (2.0f * f * g + EPS_C) / (f * f + g * g + EPS_C);
    float met  = dist * sqrtf(lum);
    return (1.0f - met) * 2.0f;
}

// Grid: 512 blocks x 256 threads, 2 blocks/CU (launch_bounds(256,2) -> VGPR<=256,
// 2 waves/SIMD for latency hiding; previous version ran at 1 wave/SIMD).
//   mg = blockIdx & 63 : 64 groups of 4 modes. Same-mg blocks have equal
//                        blockIdx mod 8 -> same XCD -> shared L2 for mode rows.
//   bg = blockIdx >> 6 : 8 groups of 8 batch rows; wave w owns rows bg*8+2w, +1.
// Phase 1: wave w computes the Frobenius norm of mode mg*4+w (one mode per wave),
//          parks it in LDS; also warms L1/L2 with the block's 4 mode rows.
// Phase 2: each wave loads its 2 input rows into registers (2 x 16 float4) and
//          butterfly-reduces their norms.
// Main loop (4 modes): stream the (now L1/L2-hot) mode row once, accumulating
// dot(b0), dot(b1) in 8 independent FMA chains (q-chains removed -> 33% less
// VALU vs previous), butterfly d0/d1, metric, running min.
// Partials -> ws[mg*64 + b]: all 4096 slots written every call (poison-immune,
// each slot written by exactly one wave). Arithmetic order per value is
// identical to the previous kernel -> bit-identical output.
__global__ __launch_bounds__(256, 2)
void simk_main(const float* __restrict__ inputs, const float* __restrict__ modes,
               float* __restrict__ ws) {
    const int tid  = threadIdx.x;
    const int lane = tid & 63;
    const int w    = tid >> 6;
    const int mg   = blockIdx.x & 63;
    const int bg   = blockIdx.x >> 6;
    const int b0   = bg * 8 + w * 2;
    const int b1   = b0 + 1;

    const float4* inp4 = (const float4*)inputs;
    const float4* mod4 = (const float4*)modes;

    __shared__ float g_sh[4];

    // Phase 1: per-wave mode norm (wave w -> mode mg*4+w)
    {
        const float4* mp = mod4 + (size_t)(mg * 4 + w) * 1024;
        float qx = 0.f, qy = 0.f, qz = 0.f, qw = 0.f;
#pragma unroll
        for (int j = 0; j < 16; ++j) {
            float4 v = mp[j * 64 + lane];
            qx += v.x * v.x; qy += v.y * v.y;
            qz += v.z * v.z; qw += v.w * v.w;
        }
        float q = (qx + qy) + (qz + qw);
#pragma unroll
        for (int sh = 1; sh < 64; sh <<= 1) q += __shfl_xor(q, sh, 64);
        if (lane == 0) g_sh[w] = sqrtf(q);
    }

    // Phase 2: input rows into registers + norms (overlaps phase-1 latency tail)
    float4 in0[16], in1[16];
#pragma unroll
    for (int j = 0; j < 16; ++j) in0[j] = inp4[(size_t)b0 * 1024 + j * 64 + lane];
#pragma unroll
    for (int j = 0; j < 16; ++j) in1[j] = inp4[(size_t)b1 * 1024 + j * 64 + lane];

    float s0 = 0.f, s1 = 0.f;
#pragma unroll
    for (int j = 0; j < 16; ++j) {
        s0 += in0[j].x * in0[j].x + in0[j].y * in0[j].y + in0[j].z * in0[j].z + in0[j].w * in0[j].w;
        s1 += in1[j].x * in1[j].x + in1[j].y * in1[j].y + in1[j].z * in1[j].z + in1[j].w * in1[j].w;
    }
#pragma unroll
    for (int sh = 1; sh < 64; sh <<= 1) {
        s0 += __shfl_xor(s0, sh, 64);
        s1 += __shfl_xor(s1, sh, 64);
    }
    const float f0 = sqrtf(s0);
    const float f1 = sqrtf(s1);

    __syncthreads();

    float min0 = 3.0e38f, min1 = 3.0e38f;

    // unroll 1: one 16-float4 mode row in flight keeps VGPR under the 256 cap
    // (two in flight + 128 input regs would spill at 2 waves/SIMD).
#pragma unroll 1
    for (int mi = 0; mi < 4; ++mi) {
        const float4* mp = mod4 + (size_t)(mg * 4 + mi) * 1024;
        float d0x = 0.f, d0y = 0.f, d0z = 0.f, d0w = 0.f;
        float d1x = 0.f, d1y = 0.f, d1z = 0.f, d1w = 0.f;
#pragma unroll
        for (int j = 0; j < 16; ++j) {
            float4 v = mp[j * 64 + lane];
            d0x += v.x * in0[j].x; d0y += v.y * in0[j].y;
            d0z += v.z * in0[j].z; d0w += v.w * in0[j].w;
            d1x += v.x * in1[j].x; d1y += v.y * in1[j].y;
            d1z += v.z * in1[j].z; d1w += v.w * in1[j].w;
        }
        float d0 = (d0x + d0y) + (d0z + d0w);
        float d1 = (d1x + d1y) + (d1z + d1w);
#pragma unroll
        for (int sh = 1; sh < 64; sh <<= 1) {
            d0 += __shfl_xor(d0, sh, 64);
            d1 += __shfl_xor(d1, sh, 64);
        }
        const float g = g_sh[mi];
        min0 = fminf(min0, metric_val(d0, f0, g));
        min1 = fminf(min1, metric_val(d1, f1, g));
    }

    // Deterministic partial write: each (b, mg) slot written by exactly one wave.
    if (lane == 0) {
        ws[mg * 64 + b0] = min0;
        ws[mg * 64 + b1] = min1;
    }
}

// 256 threads: quarter k folds 16 of the 64 mode-group partials for row b
// (independent pipelined loads), then LDS-fold across the 4 quarters.
__global__ void simk_reduce(const float* __restrict__ ws, float* __restrict__ out) {
    __shared__ float sh[256];
    const int t = threadIdx.x;
    const int b = t & 63;
    const int k = t >> 6;
    float m = 3.0e38f;
#pragma unroll
    for (int i = 0; i < 16; ++i) m = fminf(m, ws[(k * 16 + i) * 64 + b]);
    sh[t] = m;
    __syncthreads();
    if (k == 0)
        out[b] = fminf(fminf(sh[b], sh[b + 64]), fminf(sh[b + 128], sh[b + 192]));
}

extern "C" void kernel_launch(void* const* d_in, const int* in_sizes, int n_in,
                              void* d_out, int out_size, void* d_ws, size_t ws_size,
                              hipStream_t stream) {
    const float* inputs = (const float*)d_in[0];
    const float* modes  = (const float*)d_in[1];
    float* ws  = (float*)d_ws;
    float* out = (float*)d_out;

    simk_main<<<512, 256, 0, stream>>>(inputs, modes, ws);
    simk_reduce<<<1, 256, 0, stream>>>(ws, out);
}